// Round 5
// baseline (205.853 us; speedup 1.0000x reference)
//
#include <hip/hip_runtime.h>
#include <hip/hip_cooperative_groups.h>

namespace cg = cooperative_groups;

// Problem dims (fixed by reference): B=32, S=64, E=256, H=4, D=64
constexpr int ED = 256;    // embedding dim

typedef _Float16 half8 __attribute__((ext_vector_type(8)));
typedef float floatx4 __attribute__((ext_vector_type(4)));

__device__ inline unsigned short f2h(float f) {   // fp32 -> fp16 bits (RNE)
  union { _Float16 h; unsigned short u; } c;
  c.h = (_Float16)f;
  return c.u;
}

// Phase-specific LDS, union'd (phases separated by grid.sync / __syncthreads).
struct P1sm {
  unsigned short aswz[8 * 512];   // 8 KB fp16 A-frags [kk][q][m][jj]
  float fbuf[3][16][65];          // ~12.5 KB (pad 65)
  float Mrow[16];
};
struct P2sm {
  float obuf[16][260];            // 16.6 KB (pad 260)
  unsigned short easwz[8 * 512];  // 8 KB
  float Mrow[16];
};

// ---------------------------------------------------------------------------
// ONE cooperative kernel, 512 blocks x 256 thr (2 blocks/CU, co-resident).
// P0: E = exp(W) swizzled (1/512 per block, no duplication) + x staging.
// P1: qkv MFMA + fused softmax(q+k) epilogue -> AS/VS  (R0's proven body).
// P2: attn@v + o-linear (o-cols split 4-way so all 512 blocks work).
// ---------------------------------------------------------------------------
__global__ __launch_bounds__(256, 2) void tropical_fused(
    const float* __restrict__ x,
    const float* __restrict__ Wq, const float* __restrict__ Wk,
    const float* __restrict__ Wv, const float* __restrict__ Wo,
    const float* __restrict__ bq, const float* __restrict__ bk,
    const float* __restrict__ bv, const float* __restrict__ bo,
    unsigned short* __restrict__ ES, unsigned short* __restrict__ AS,
    unsigned short* __restrict__ VS, float* __restrict__ y)
{
  __shared__ union { P1sm p1; P2sm p2; } sm;
  int t = threadIdx.x, w = t >> 6, lane = t & 63;
  int bid = blockIdx.x;
  cg::grid_group grid = cg::this_grid();

  // ===================== P0: exp(W) -> ES, and x staging =====================
  int mt = bid >> 2, h = bid & 3;          // P1 block role
  int row0 = mt * 16;

  // x loads first (latency overlaps E-compute)
  float4 xv[4];
#pragma unroll
  for (int i = 0; i < 4; ++i)
    xv[i] = *(const float4*)&x[(size_t)(row0 + 4 * w + i) * ED + lane * 4];

  // E slice: z = bid>>7 selects matrix; 2 n-cols x 8 kk x 32 kl per block.
  // Swizzled layout (B-frag for mfma 16x16x32): out[(kk*256+n)*32 + kl],
  // kl = 8q+jj encodes k = 32kk+8q+jj;  exp(W[n][32kk+kl]).
  {
    int z = bid >> 7;
    const float* Wz = (z == 0) ? Wq : (z == 1) ? Wk : (z == 2) ? Wv : Wo;
    unsigned short* outz = ES + z * 65536;
    int n = (bid & 127) * 2 + (t >> 7);
    int kl = t & 31;
#pragma unroll
    for (int i = 0; i < 2; ++i) {
      int kk = ((t >> 5) & 3) + 4 * i;
      outz[(kk * 256 + n) * 32 + kl] = f2h(__expf(Wz[n * ED + 32 * kk + kl]));
    }
  }

  // x staging: wave w stages rows 4w..4w+3 as fp16 A-fragments
#pragma unroll
  for (int i = 0; i < 4; ++i) {
    int r = 4 * w + i;
    float m = fmaxf(fmaxf(xv[i].x, xv[i].y), fmaxf(xv[i].z, xv[i].w));
#pragma unroll
    for (int off = 32; off > 0; off >>= 1) m = fmaxf(m, __shfl_xor(m, off));
    ushort4 pk;
    pk.x = f2h(__expf(xv[i].x - m));
    pk.y = f2h(__expf(xv[i].y - m));
    pk.z = f2h(__expf(xv[i].z - m));
    pk.w = f2h(__expf(xv[i].w - m));
    int k0 = lane * 4;                       // kk=k0>>5, q=(k0>>3)&3, jj=k0&7
    int idx = (k0 >> 5) * 512 + ((k0 >> 3) & 3) * 128 + r * 8 + (k0 & 7);
    *(ushort4*)&sm.p1.aswz[idx] = pk;
    if (lane == 0) sm.p1.Mrow[r] = m;
  }

  grid.sync();   // E visible device-wide; staging visible block-wide

  // ===================== P1: qkv MFMA + softmax epilogue =====================
  {
    // B-fragments from ES (L2-hot)
    int bb = ((h * 64 + w * 16 + (lane & 15)) << 2) + (lane >> 4);
    const half8* BQ = (const half8*)ES;
    const half8* BK = (const half8*)(ES + 65536);
    const half8* BV = (const half8*)(ES + 131072);
    half8 bqf[8], bkf[8], bvf[8];
#pragma unroll
    for (int kk = 0; kk < 8; ++kk) {
      bqf[kk] = BQ[kk * 1024 + bb];
      bkf[kk] = BK[kk * 1024 + bb];
      bvf[kk] = BV[kk * 1024 + bb];
    }

    // A fragments: lane-consecutive 16B chunks, conflict-free b128
    half8 afrag[8];
#pragma unroll
    for (int kk = 0; kk < 8; ++kk)
      afrag[kk] = *(const half8*)&sm.p1.aswz[kk * 512 + lane * 8];

    floatx4 accq = {0.f, 0.f, 0.f, 0.f};
    floatx4 acck = {0.f, 0.f, 0.f, 0.f};
    floatx4 accv = {0.f, 0.f, 0.f, 0.f};
#pragma unroll
    for (int kk = 0; kk < 8; ++kk) {
      accq = __builtin_amdgcn_mfma_f32_16x16x32_f16(afrag[kk], bqf[kk], accq, 0, 0, 0);
      acck = __builtin_amdgcn_mfma_f32_16x16x32_f16(afrag[kk], bkf[kk], acck, 0, 0, 0);
      accv = __builtin_amdgcn_mfma_f32_16x16x32_f16(afrag[kk], bvf[kk], accv, 0, 0, 0);
    }

    // C frags -> LDS (D: col=lane&15, row=4*(lane>>4)+reg)
    {
      int c = w * 16 + (lane & 15);
      int rb = (lane >> 4) * 4;
#pragma unroll
      for (int reg = 0; reg < 4; ++reg) {
        sm.p1.fbuf[0][rb + reg][c] = accq[reg];
        sm.p1.fbuf[1][rb + reg][c] = acck[reg];
        sm.p1.fbuf[2][rb + reg][c] = accv[reg];
      }
    }
    __syncthreads();

    // epilogue: wave w owns rows 4w..4w+3; lane = col (d) within head
    int cg_ = h * 64 + lane;
    float bqv = bq[cg_], bkv = bk[cg_], bvv = bv[cg_];
    int b = row0 >> 6;
    int mt16 = (row0 >> 4) & 3;
    size_t asBase = (size_t)(((b * 4 + mt16) * 4) + h) * 1024
                  + (lane >> 5) * 512 + ((lane >> 3) & 3) * 128 + (lane & 7);
#pragma unroll
    for (int i = 0; i < 4; ++i) {
      int r = 4 * w + i;
      float Mr = sm.p1.Mrow[r];
      float qv = Mr + __logf(sm.p1.fbuf[0][r][lane]) + bqv;
      float kv = Mr + __logf(sm.p1.fbuf[1][r][lane]) + bkv;
      float vv = Mr + __logf(sm.p1.fbuf[2][r][lane]) + bvv;
      // v -> B-frag-swizzled VS: k = d = mt16*16 + r, n = cg_
      int d = mt16 * 16 + r;
      VS[(size_t)(b * 2 + (d >> 5)) * 8192 + cg_ * 32 + ((d >> 3) & 3) * 8 + (d & 7)]
          = f2h(vv);
      // softmax of q+k over the 64-lane head segment
      float s = qv + kv;
      float smx = s;
#pragma unroll
      for (int off = 32; off > 0; off >>= 1) smx = fmaxf(smx, __shfl_xor(smx, off));
      float ex = __expf(s - smx);
      float den = ex;
#pragma unroll
      for (int off = 32; off > 0; off >>= 1) den += __shfl_xor(den, off);
      // attn -> A-frag-swizzled AS: m = r, k = lane
      AS[asBase + r * 8] = f2h(ex / den);
    }
  }

  grid.sync();   // AS/VS visible device-wide

  // ===================== P2: attn@v + o-linear (quarter) =====================
  {
    int b2 = bid >> 4, mt2 = (bid >> 2) & 3, qtr = bid & 3;
    int row2 = b2 * 64 + mt2 * 16;
    int q = lane >> 4, nl = lane & 15;
    int rb = q * 4;

    // attn@v (full 256 cols): wave w = head w
    const half8* AS8 = (const half8*)(AS + (size_t)(((b2 * 4 + mt2) * 4) + w) * 1024);
    const half8* VS8 = (const half8*)VS;
    half8 af0 = AS8[lane], af1 = AS8[64 + lane];
    floatx4 acc[4];
#pragma unroll
    for (int nt = 0; nt < 4; ++nt) acc[nt] = (floatx4){0.f, 0.f, 0.f, 0.f};
#pragma unroll
    for (int nt = 0; nt < 4; ++nt) {
      int n = w * 64 + nt * 16 + nl;
      half8 b0 = VS8[(size_t)(b2 * 2 + 0) * 1024 + n * 4 + q];
      half8 b1 = VS8[(size_t)(b2 * 2 + 1) * 1024 + n * 4 + q];
      acc[nt] = __builtin_amdgcn_mfma_f32_16x16x32_f16(af0, b0, acc[nt], 0, 0, 0);
      acc[nt] = __builtin_amdgcn_mfma_f32_16x16x32_f16(af1, b1, acc[nt], 0, 0, 0);
    }
#pragma unroll
    for (int nt = 0; nt < 4; ++nt)
#pragma unroll
      for (int reg = 0; reg < 4; ++reg)
        sm.p2.obuf[rb + reg][w * 64 + nt * 16 + nl] = acc[nt][reg];
    __syncthreads();

    // rowmax + exp + A-frag swizzle for the o-linear (full row)
#pragma unroll
    for (int i = 0; i < 4; ++i) {
      int r = 4 * w + i;
      float4 o4 = *(const float4*)&sm.p2.obuf[r][lane * 4];
      float m = fmaxf(fmaxf(o4.x, o4.y), fmaxf(o4.z, o4.w));
#pragma unroll
      for (int off = 32; off > 0; off >>= 1) m = fmaxf(m, __shfl_xor(m, off));
      ushort4 pk;
      pk.x = f2h(__expf(o4.x - m));
      pk.y = f2h(__expf(o4.y - m));
      pk.z = f2h(__expf(o4.z - m));
      pk.w = f2h(__expf(o4.w - m));
      int k0 = lane * 4;
      int idx = (k0 >> 5) * 512 + ((k0 >> 3) & 3) * 128 + r * 8 + (k0 & 7);
      *(ushort4*)&sm.p2.easwz[idx] = pk;
      if (lane == 0) sm.p2.Mrow[r] = m;
    }
    __syncthreads();

    // o-linear MFMA: this quarter's 64 cols; wave w -> 16 cols
    half8 af2[8];
#pragma unroll
    for (int kk = 0; kk < 8; ++kk)
      af2[kk] = *(const half8*)&sm.p2.easwz[kk * 512 + lane * 8];
    const half8* BO = (const half8*)(ES + 3 * 65536);
    int n = qtr * 64 + w * 16 + nl;
    floatx4 acc2 = {0.f, 0.f, 0.f, 0.f};
#pragma unroll
    for (int kk = 0; kk < 8; ++kk)
      acc2 = __builtin_amdgcn_mfma_f32_16x16x32_f16(
          af2[kk], BO[kk * 1024 + n * 4 + q], acc2, 0, 0, 0);
#pragma unroll
    for (int reg = 0; reg < 4; ++reg)
      sm.p2.obuf[rb + reg][n] = acc2[reg];
    __syncthreads();

    // epilogue: log + bias over this quarter's 64 cols (1 col/lane)
    int c = qtr * 64 + lane;
    float bov = bo[c];
#pragma unroll
    for (int i = 0; i < 4; ++i) {
      int r = 4 * w + i;
      y[(size_t)(row2 + r) * ED + c] = sm.p2.Mrow[r] + __logf(sm.p2.obuf[r][c]) + bov;
    }
  }
}

// ---------------------------------------------------------------------------
extern "C" void kernel_launch(void* const* d_in, const int* in_sizes, int n_in,
                              void* d_out, int out_size, void* d_ws, size_t ws_size,
                              hipStream_t stream) {
  const float* x  = (const float*)d_in[0];
  const float* Wq = (const float*)d_in[1];
  const float* bq = (const float*)d_in[2];
  const float* Wk = (const float*)d_in[3];
  const float* bk = (const float*)d_in[4];
  const float* Wv = (const float*)d_in[5];
  const float* bv = (const float*)d_in[6];
  const float* Wo = (const float*)d_in[7];
  const float* bo = (const float*)d_in[8];
  float* y = (float*)d_out;

  // ws (bytes): ES 512K (4 x 128K swizzled exp(W)) | AS 1M | VS 1M
  char* ws = (char*)d_ws;
  unsigned short* ES = (unsigned short*)(ws);
  unsigned short* AS = (unsigned short*)(ws + 524288);
  unsigned short* VS = (unsigned short*)(ws + 524288 + 1048576);

  void* args[] = {(void*)&x, (void*)&Wq, (void*)&Wk, (void*)&Wv, (void*)&Wo,
                  (void*)&bq, (void*)&bk, (void*)&bv, (void*)&bo,
                  (void*)&ES, (void*)&AS, (void*)&VS, (void*)&y};
  hipLaunchCooperativeKernel((void*)tropical_fused, dim3(512), dim3(256),
                             args, 0, stream);
}

// Round 6
// 86.787 us; speedup vs baseline: 2.3719x; 2.3719x over previous
//
#include <hip/hip_runtime.h>

// Problem dims (fixed by reference): B=32, S=64, E=256, H=4, D=64
constexpr int ED = 256;    // embedding dim
constexpr int SD = 64;     // seq len
constexpr int BD = 32;     // batch
constexpr int NROWS = BD * SD;  // 2048 rows of (E)

typedef _Float16 half8 __attribute__((ext_vector_type(8)));
typedef float floatx4 __attribute__((ext_vector_type(4)));

__device__ inline unsigned short f2h(float f) {   // fp32 -> fp16 bits (RNE)
  union { _Float16 h; unsigned short u; } c;
  c.h = (_Float16)f;
  return c.u;
}

// ---------------------------------------------------------------------------
// Kernel A: B-fragment-swizzled fp16 exp(W) for all 4 weight matrices.
// B[k][n] = exp(W[n][k]); frag layout for mfma_f32_16x16x32 (lane l:
// n = l&15, k = 32*kk + 8*(l>>4) + jj): ushort idx = (kk*256+n)*32 + q*8+jj.
// grid (32,4), block 256.
// ---------------------------------------------------------------------------
__global__ __launch_bounds__(256) void expT_swz_kernel(
    const float* __restrict__ Wq, const float* __restrict__ Wk,
    const float* __restrict__ Wv, const float* __restrict__ Wo,
    unsigned short* __restrict__ EqS, unsigned short* __restrict__ EkS,
    unsigned short* __restrict__ EvS, unsigned short* __restrict__ EoS)
{
  int z = blockIdx.y;
  const float* W = (z == 0) ? Wq : (z == 1) ? Wk : (z == 2) ? Wv : Wo;
  unsigned short* out = (z == 0) ? EqS : (z == 1) ? EkS : (z == 2) ? EvS : EoS;
  int t = threadIdx.x;
  int n = blockIdx.x * 8 + (t >> 5), kl = t & 31;
#pragma unroll
  for (int kk = 0; kk < 8; ++kk)
    out[(kk * 256 + n) * 32 + kl] = f2h(__expf(W[n * ED + 32 * kk + kl]));
}

// ---------------------------------------------------------------------------
// Kernel B: MFMA qkv. Block = 4 waves = M-tile 16 rows x one head (64 cols).
// grid 512 = 128 m-tiles x 4 heads (2 blocks/CU). launch_bounds(256,2):
// lets the 24 B-fragments + 4 x-rows be loaded into registers UP FRONT
// (~112 VGPRs) so L2 latency overlaps the exp/shuffle prologue.
// Epilogue: fused 64-wide softmax(q+k); writes attn in A-frag-swizzled fp16
// (AS) and v in B-frag-swizzled fp16 (VS).
// ---------------------------------------------------------------------------
__global__ __launch_bounds__(256, 2) void qkv_mfma_kernel(
    const float* __restrict__ x,
    const unsigned short* __restrict__ EqS, const unsigned short* __restrict__ EkS,
    const unsigned short* __restrict__ EvS,
    const float* __restrict__ bq, const float* __restrict__ bk,
    const float* __restrict__ bv,
    unsigned short* __restrict__ AS, unsigned short* __restrict__ VS)
{
  int t = threadIdx.x;
  int w = t >> 6, lane = t & 63;
  int mt = blockIdx.x >> 2, h = blockIdx.x & 3;
  int row0 = mt * 16;

  __shared__ unsigned short aswz[8 * 512];   // 8 KB fp16 A-frags [kk][q][m][jj]
  __shared__ float fbuf[3][16][65];          // ~12.5 KB (pad 65)
  __shared__ float Mrow[16];

  // --- issue ALL global loads first: 4 x-rows + 24 B-fragments ---
  float4 xv[4];
#pragma unroll
  for (int i = 0; i < 4; ++i)
    xv[i] = *(const float4*)&x[(size_t)(row0 + 4 * w + i) * ED + lane * 4];

  int bb = ((h * 64 + w * 16 + (lane & 15)) << 2) + (lane >> 4);
  const half8* BQ = (const half8*)EqS;
  const half8* BK = (const half8*)EkS;
  const half8* BV = (const half8*)EvS;
  half8 bqf[8], bkf[8], bvf[8];
#pragma unroll
  for (int kk = 0; kk < 8; ++kk) {
    bqf[kk] = BQ[kk * 1024 + bb];
    bkf[kk] = BK[kk * 1024 + bb];
    bvf[kk] = BV[kk * 1024 + bb];
  }

  // --- prologue: wave w stages rows 4w..4w+3 as fp16 A-fragments ---
#pragma unroll
  for (int i = 0; i < 4; ++i) {
    int r = 4 * w + i;
    float m = fmaxf(fmaxf(xv[i].x, xv[i].y), fmaxf(xv[i].z, xv[i].w));
#pragma unroll
    for (int off = 32; off > 0; off >>= 1) m = fmaxf(m, __shfl_xor(m, off));
    ushort4 pk;
    pk.x = f2h(__expf(xv[i].x - m));
    pk.y = f2h(__expf(xv[i].y - m));
    pk.z = f2h(__expf(xv[i].z - m));
    pk.w = f2h(__expf(xv[i].w - m));
    int k0 = lane * 4;                       // kk=k0>>5, q=(k0>>3)&3, jj=k0&7
    int idx = (k0 >> 5) * 512 + ((k0 >> 3) & 3) * 128 + r * 8 + (k0 & 7);
    *(ushort4*)&aswz[idx] = pk;
    if (lane == 0) Mrow[r] = m;
  }
  __syncthreads();

  // --- A fragments: lane-consecutive 16B chunks, conflict-free b128 ---
  half8 afrag[8];
#pragma unroll
  for (int kk = 0; kk < 8; ++kk)
    afrag[kk] = *(const half8*)&aswz[kk * 512 + lane * 8];

  // --- MFMA main loop: B frags already in registers ---
  floatx4 accq = {0.f, 0.f, 0.f, 0.f};
  floatx4 acck = {0.f, 0.f, 0.f, 0.f};
  floatx4 accv = {0.f, 0.f, 0.f, 0.f};
#pragma unroll
  for (int kk = 0; kk < 8; ++kk) {
    accq = __builtin_amdgcn_mfma_f32_16x16x32_f16(afrag[kk], bqf[kk], accq, 0, 0, 0);
    acck = __builtin_amdgcn_mfma_f32_16x16x32_f16(afrag[kk], bkf[kk], acck, 0, 0, 0);
    accv = __builtin_amdgcn_mfma_f32_16x16x32_f16(afrag[kk], bvf[kk], accv, 0, 0, 0);
  }

  // --- C frags -> LDS (D: col=lane&15, row=4*(lane>>4)+reg) ---
  {
    int c = w * 16 + (lane & 15);
    int rb = (lane >> 4) * 4;
#pragma unroll
    for (int reg = 0; reg < 4; ++reg) {
      fbuf[0][rb + reg][c] = accq[reg];
      fbuf[1][rb + reg][c] = acck[reg];
      fbuf[2][rb + reg][c] = accv[reg];
    }
  }
  __syncthreads();

  // --- epilogue: wave w owns rows 4w..4w+3; lane = col (d) within head ---
  int cg = h * 64 + lane;
  float bqv = bq[cg], bkv = bk[cg], bvv = bv[cg];
  int b = row0 >> 6;
  int mt16 = (row0 >> 4) & 3;
  size_t asBase = (size_t)(((b * 4 + mt16) * 4) + h) * 1024
                + (lane >> 5) * 512 + ((lane >> 3) & 3) * 128 + (lane & 7);
#pragma unroll
  for (int i = 0; i < 4; ++i) {
    int r = 4 * w + i;
    float Mr = Mrow[r];
    float qv = Mr + __logf(fbuf[0][r][lane]) + bqv;
    float kv = Mr + __logf(fbuf[1][r][lane]) + bkv;
    float vv = Mr + __logf(fbuf[2][r][lane]) + bvv;
    // v -> B-frag-swizzled VS: k = d = mt16*16 + r, n = cg
    int d = mt16 * 16 + r;
    VS[(size_t)(b * 2 + (d >> 5)) * 8192 + cg * 32 + ((d >> 3) & 3) * 8 + (d & 7)]
        = f2h(vv);
    // softmax of q+k over the 64-lane head segment
    float s = qv + kv;
    float sm = s;
#pragma unroll
    for (int off = 32; off > 0; off >>= 1) sm = fmaxf(sm, __shfl_xor(sm, off));
    float ex = __expf(s - sm);
    float den = ex;
#pragma unroll
    for (int off = 32; off > 0; off >>= 1) den += __shfl_xor(den, off);
    // attn -> A-frag-swizzled AS: m = r, k = lane
    AS[asBase + r * 8] = f2h(ex / den);
  }
}

// ---------------------------------------------------------------------------
// Kernel C: fused MFMA attn@v + output tropical linear.
// grid 256 = (b, mt, half): block = 4 waves. Each block does the FULL
// attn@v (wave w = head w, 8 MFMAs — duplicated across the 2 halves) and
// full rowmax/exp, then the o-linear for its 128-col half only
// (16 MFMAs/wave instead of 32). Doubles CU coverage, shortens the chain.
// ---------------------------------------------------------------------------
__global__ __launch_bounds__(256, 2) void avo_mfma_kernel(
    const unsigned short* __restrict__ AS, const unsigned short* __restrict__ VS,
    const unsigned short* __restrict__ EoS, const float* __restrict__ bo,
    float* __restrict__ y)
{
  int t = threadIdx.x, w = t >> 6, lane = t & 63;
  int blk = blockIdx.x;
  int b = blk >> 3, mt = (blk >> 1) & 3, hf = blk & 1;
  int row0 = b * 64 + mt * 16;
  int q = lane >> 4, nl = lane & 15;

  __shared__ float obuf[16][260];            // 16.6 KB (pad 260)
  __shared__ unsigned short easwz[8 * 512];  // 8 KB
  __shared__ float Mrow[16];

  // ---- attn@v (full 256 cols): wave w = head w ----
  const half8* AS8 = (const half8*)(AS + (size_t)(((b * 4 + mt) * 4) + w) * 1024);
  const half8* VS8 = (const half8*)VS;
  half8 af0 = AS8[lane], af1 = AS8[64 + lane];
  floatx4 acc[4];
#pragma unroll
  for (int nt = 0; nt < 4; ++nt) acc[nt] = (floatx4){0.f, 0.f, 0.f, 0.f};
#pragma unroll
  for (int nt = 0; nt < 4; ++nt) {
    int n = w * 64 + nt * 16 + nl;
    half8 b0 = VS8[(size_t)(b * 2 + 0) * 1024 + n * 4 + q];
    half8 b1 = VS8[(size_t)(b * 2 + 1) * 1024 + n * 4 + q];
    acc[nt] = __builtin_amdgcn_mfma_f32_16x16x32_f16(af0, b0, acc[nt], 0, 0, 0);
    acc[nt] = __builtin_amdgcn_mfma_f32_16x16x32_f16(af1, b1, acc[nt], 0, 0, 0);
  }
  int rb = q * 4;
#pragma unroll
  for (int nt = 0; nt < 4; ++nt)
#pragma unroll
    for (int reg = 0; reg < 4; ++reg)
      obuf[rb + reg][w * 64 + nt * 16 + nl] = acc[nt][reg];
  __syncthreads();

  // ---- rowmax + exp + A-frag swizzle for the o-linear (full row) ----
#pragma unroll
  for (int i = 0; i < 4; ++i) {
    int r = 4 * w + i;
    float4 o4 = *(const float4*)&obuf[r][lane * 4];
    float m = fmaxf(fmaxf(o4.x, o4.y), fmaxf(o4.z, o4.w));
#pragma unroll
    for (int off = 32; off > 0; off >>= 1) m = fmaxf(m, __shfl_xor(m, off));
    ushort4 pk;
    pk.x = f2h(__expf(o4.x - m));
    pk.y = f2h(__expf(o4.y - m));
    pk.z = f2h(__expf(o4.z - m));
    pk.w = f2h(__expf(o4.w - m));
    int k0 = lane * 4;
    int idx = (k0 >> 5) * 512 + ((k0 >> 3) & 3) * 128 + r * 8 + (k0 & 7);
    *(ushort4*)&easwz[idx] = pk;
    if (lane == 0) Mrow[r] = m;
  }
  __syncthreads();

  // ---- o-linear MFMA: this half's 128 cols; wave w -> 32 cols ----
  half8 af2[8];
#pragma unroll
  for (int kk = 0; kk < 8; ++kk)
    af2[kk] = *(const half8*)&easwz[kk * 512 + lane * 8];
  const half8* BO = (const half8*)EoS;
  floatx4 acc2[2];
  acc2[0] = (floatx4){0.f, 0.f, 0.f, 0.f};
  acc2[1] = (floatx4){0.f, 0.f, 0.f, 0.f};
#pragma unroll
  for (int kk = 0; kk < 8; ++kk) {
#pragma unroll
    for (int nt = 0; nt < 2; ++nt) {
      int n = hf * 128 + w * 32 + nt * 16 + nl;
      acc2[nt] = __builtin_amdgcn_mfma_f32_16x16x32_f16(
          af2[kk], BO[kk * 1024 + n * 4 + q], acc2[nt], 0, 0, 0);
    }
  }
#pragma unroll
  for (int nt = 0; nt < 2; ++nt)
#pragma unroll
    for (int reg = 0; reg < 4; ++reg)
      obuf[rb + reg][hf * 128 + w * 32 + nt * 16 + nl] = acc2[nt][reg];
  __syncthreads();

  // ---- epilogue: log + bias, float2 stores over this half's 128 cols ----
  int c0 = hf * 128 + lane * 2;
  float2 bo2 = *(const float2*)&bo[c0];
#pragma unroll
  for (int i = 0; i < 4; ++i) {
    int r = 4 * w + i;
    float2 f2 = *(const float2*)&obuf[r][c0];
    float M = Mrow[r];
    float2 y2;
    y2.x = M + __logf(f2.x) + bo2.x;
    y2.y = M + __logf(f2.y) + bo2.y;
    *(float2*)&y[(size_t)(row0 + r) * ED + c0] = y2;
  }
}

// ---------------------------------------------------------------------------
extern "C" void kernel_launch(void* const* d_in, const int* in_sizes, int n_in,
                              void* d_out, int out_size, void* d_ws, size_t ws_size,
                              hipStream_t stream) {
  const float* x  = (const float*)d_in[0];
  const float* Wq = (const float*)d_in[1];
  const float* bq = (const float*)d_in[2];
  const float* Wk = (const float*)d_in[3];
  const float* bk = (const float*)d_in[4];
  const float* Wv = (const float*)d_in[5];
  const float* bv = (const float*)d_in[6];
  const float* Wo = (const float*)d_in[7];
  const float* bo = (const float*)d_in[8];
  float* y = (float*)d_out;

  // ws (bytes): EqS/EkS/EvS/EoS 128K each | AS 1M | VS 1M  (total 2.5 MB)
  char* ws = (char*)d_ws;
  unsigned short* EqS = (unsigned short*)(ws);
  unsigned short* EkS = (unsigned short*)(ws + 131072);
  unsigned short* EvS = (unsigned short*)(ws + 262144);
  unsigned short* EoS = (unsigned short*)(ws + 393216);
  unsigned short* AS  = (unsigned short*)(ws + 524288);
  unsigned short* VS  = (unsigned short*)(ws + 524288 + 1048576);

  expT_swz_kernel<<<dim3(32, 4), 256, 0, stream>>>(Wq, Wk, Wv, Wo,
                                                   EqS, EkS, EvS, EoS);
  qkv_mfma_kernel<<<512, 256, 0, stream>>>(x, EqS, EkS, EvS, bq, bk, bv,
                                           AS, VS);
  avo_mfma_kernel<<<256, 256, 0, stream>>>(AS, VS, EoS, bo, y);
}